// Round 1
// baseline (1700.046 us; speedup 1.0000x reference)
//
#include <hip/hip_runtime.h>
#include <math.h>

// TriDirectionalMamba: C=64, N=16, DI=128, K=4, DT_RANK=4, L=48, 48^3 grid, B=1.
// 3 directional passes (seq axis = D, H, W), each 2304 sequences of length 48.
// One block (128 threads) = one sequence. Three sequential launches accumulate
// softmax(alpha)-weighted results into d_out (dir0 writes, dir1/2 RMW-add).

#define L_   48
#define CS   110592      // channel stride in x = 48*48*48
#define L2E  1.44269504088896340736f

__device__ __forceinline__ float fast_silu(float x) {
    return x / (1.0f + __expf(-x));
}

template<int DIR, bool FIRST>
__global__ __launch_bounds__(128, 2)
void mamba_dir(const float* __restrict__ x,
               const float* __restrict__ in_proj,
               const float* __restrict__ conv_w,
               const float* __restrict__ conv_b,
               const float* __restrict__ x_proj,
               const float* __restrict__ dt_w,
               const float* __restrict__ dt_b,
               const float* __restrict__ A_log,
               const float* __restrict__ D_ssm,
               const float* __restrict__ out_proj,
               const float* __restrict__ ln_g,
               const float* __restrict__ ln_b,
               const float* __restrict__ alpha,
               float* __restrict__ out)
{
    // xs_s[48][68]: pad 68 -> rows 272B (16B aligned), quad banks rotate by t.
    __shared__ float xs_s[48 * 68];
    // u_s[48][128]: XOR quad-swizzle (g ^ (t&7)) -> conflict-free cols AND rows.
    __shared__ float u_s[48 * 128];
    // xd_s[48][40]: rows 160B (16B aligned); [0:4]=dlt, [4:20]=B, [20:36]=C.
    __shared__ float xd_s[48 * 40];

    const int tid  = threadIdx.x;
    const int lane = tid & 63;
    const int wv   = __builtin_amdgcn_readfirstlane(tid >> 6);  // wave id 0/1
    const int s    = blockIdx.x;

    int base, TS;
    if (DIR == 0)      { base = s;                                TS = 2304; }
    else if (DIR == 1) { base = (s / 48) * 2304 + (s % 48);       TS = 48;   }
    else               { base = (s / 48) * 2304 + (s % 48) * 48;  TS = 1;    }

    const float* ip  = in_proj  + DIR * 256 * 64;
    const float* xp  = x_proj   + DIR * 36 * 128;
    const float* op  = out_proj + DIR * 64 * 128;

    // softmax(alpha) weight for this direction (scalar, uniform)
    float a0 = alpha[0], a1 = alpha[1], a2 = alpha[2];
    float mx = fmaxf(a0, fmaxf(a1, a2));
    float e0 = __expf(a0 - mx), e1 = __expf(a1 - mx), e2 = __expf(a2 - mx);
    float wdir = ((DIR == 0) ? e0 : (DIR == 1) ? e1 : e2) / (e0 + e1 + e2);

    // ---- Phase 0: global -> xs_s (t-major mapping keeps dir2 coalesced) ----
    for (int o = tid; o < 48 * 64; o += 128) {
        int t = o % 48, c = o / 48;
        xs_s[t * 68 + c] = x[c * CS + base + t * TS];
    }
    __syncthreads();

    // ---- Phase 1: LayerNorm, rows in registers (both waves; lane = t) ----
    const int t = lane;
    float xr[64];
    if (t < 48) {
        const float4* row = (const float4*)&xs_s[t * 68];
#pragma unroll
        for (int q = 0; q < 16; q++) {
            float4 v = row[q];
            xr[4*q+0] = v.x; xr[4*q+1] = v.y; xr[4*q+2] = v.z; xr[4*q+3] = v.w;
        }
        float m = 0.f;
#pragma unroll
        for (int c = 0; c < 64; c++) m += xr[c];
        m *= (1.0f / 64.0f);
        float var = 0.f;
#pragma unroll
        for (int c = 0; c < 64; c++) { float d0 = xr[c] - m; var += d0 * d0; }
        var *= (1.0f / 64.0f);
        float rs = rsqrtf(var + 1e-5f);
#pragma unroll
        for (int c = 0; c < 64; c++)
            xr[c] = (xr[c] - m) * rs * ln_g[DIR * 64 + c] + ln_b[DIR * 64 + c];
    }
    __syncthreads();           // all row reads done before wave0 writes back
    if (t < 48 && wv == 0) {   // normalized xs needed again in phase 6
        float4* row = (float4*)&xs_s[t * 68];
#pragma unroll
        for (int q = 0; q < 16; q++) {
            float4 v; v.x = xr[4*q+0]; v.y = xr[4*q+1]; v.z = xr[4*q+2]; v.w = xr[4*q+3];
            row[q] = v;
        }
    }

    // ---- Phase 2: in_proj (xin half only; j split by wave), s_load weights ----
    if (t < 48) {
        for (int jj = 0; jj < 64; jj++) {
            int j = wv * 64 + jj;
            const float4* wrow = (const float4*)(ip + j * 64);
            float acc = 0.f;
#pragma unroll
            for (int q = 0; q < 16; q++) {
                float4 w4 = wrow[q];
                acc += xr[4*q+0] * w4.x + xr[4*q+1] * w4.y
                     + xr[4*q+2] * w4.z + xr[4*q+3] * w4.w;
            }
            int col = (((j >> 2) ^ (t & 7)) << 2) | (j & 3);
            u_s[t * 128 + col] = acc;
        }
    }
    __syncthreads();

    // ---- Phase 3: depthwise causal conv(K=4) + SiLU, in place (thread = d) ----
    {
        const int d = tid;
        float4 cw = *(const float4*)(conv_w + DIR * 512 + d * 4);
        float cb  = conv_b[DIR * 128 + d];
        float w0 = 0.f, w1 = 0.f, w2 = 0.f;
        for (int tt = 0; tt < 48; tt++) {
            int col = tt * 128 + ((((d >> 2) ^ (tt & 7)) << 2) | (d & 3));
            float w3 = u_s[col];
            float xc = cw.x * w0 + cw.y * w1 + cw.z * w2 + cw.w * w3 + cb;
            u_s[col] = fast_silu(xc);
            w0 = w1; w1 = w2; w2 = w3;
        }
    }
    __syncthreads();

    // ---- Phase 4: x_proj u(128) -> x_dbl(36) (lane = t; j split by wave) ----
    if (t < 48) {
        float ur[128];
        const float4* urow = (const float4*)&u_s[t * 128];
#pragma unroll
        for (int g = 0; g < 32; g++) {
            float4 v = urow[g ^ (t & 7)];
            ur[4*g+0] = v.x; ur[4*g+1] = v.y; ur[4*g+2] = v.z; ur[4*g+3] = v.w;
        }
        for (int jj = 0; jj < 18; jj++) {
            int j = wv * 18 + jj;
            const float4* wrow = (const float4*)(xp + j * 128);
            float acc = 0.f;
#pragma unroll
            for (int q = 0; q < 32; q++) {
                float4 w4 = wrow[q];
                acc += ur[4*q+0] * w4.x + ur[4*q+1] * w4.y
                     + ur[4*q+2] * w4.z + ur[4*q+3] * w4.w;
            }
            xd_s[t * 40 + j] = acc;
        }
    }
    __syncthreads();

    // ---- Phase 5: selective scan (thread = d), y+u*D written over u_s ----
    {
        const int d = tid;
        float A2[16];
        bool powok = true;
#pragma unroll
        for (int n = 0; n < 16; n++) {
            float a = -__expf(A_log[DIR * 2048 + d * 16 + n]);
            powok = powok && (fabsf(a + (float)(n + 1)) < 1e-3f);
            A2[n] = a * L2E;
        }
        float4 dtw = *(const float4*)(dt_w + DIR * 512 + d * 4);
        float dtbv = dt_b[DIR * 128 + d];
        float dsv  = D_ssm[DIR * 128 + d];
        float h[16];
#pragma unroll
        for (int n = 0; n < 16; n++) h[n] = 0.f;

#define SCAN_BODY(EXP_BLOCK)                                                   \
        for (int tt = 0; tt < 48; tt++) {                                      \
            const float* xrow = &xd_s[tt * 40];                                \
            float4 dl4 = *(const float4*)xrow;                                 \
            float dl = dtbv + dtw.x*dl4.x + dtw.y*dl4.y + dtw.z*dl4.z + dtw.w*dl4.w; \
            float delta = (dl > 20.f) ? dl : log1pf(__expf(dl));               \
            int col = tt * 128 + ((((d >> 2) ^ (tt & 7)) << 2) | (d & 3));     \
            float uu = u_s[col];                                               \
            float du = delta * uu;                                             \
            float e[16];                                                       \
            EXP_BLOCK                                                          \
            float4 Bv0 = *(const float4*)(xrow + 4);                           \
            float4 Bv1 = *(const float4*)(xrow + 8);                           \
            float4 Bv2 = *(const float4*)(xrow + 12);                          \
            float4 Bv3 = *(const float4*)(xrow + 16);                          \
            float4 Cv0 = *(const float4*)(xrow + 20);                          \
            float4 Cv1 = *(const float4*)(xrow + 24);                          \
            float4 Cv2 = *(const float4*)(xrow + 28);                          \
            float4 Cv3 = *(const float4*)(xrow + 32);                          \
            float Bf[16] = {Bv0.x,Bv0.y,Bv0.z,Bv0.w, Bv1.x,Bv1.y,Bv1.z,Bv1.w,  \
                            Bv2.x,Bv2.y,Bv2.z,Bv2.w, Bv3.x,Bv3.y,Bv3.z,Bv3.w}; \
            float Cf[16] = {Cv0.x,Cv0.y,Cv0.z,Cv0.w, Cv1.x,Cv1.y,Cv1.z,Cv1.w,  \
                            Cv2.x,Cv2.y,Cv2.z,Cv2.w, Cv3.x,Cv3.y,Cv3.z,Cv3.w}; \
            float y = 0.f;                                                     \
            _Pragma("unroll")                                                  \
            for (int n = 0; n < 16; n++) {                                     \
                h[n] = e[n] * h[n] + du * Bf[n];                               \
                y += h[n] * Cf[n];                                             \
            }                                                                  \
            u_s[col] = y + uu * dsv;                                           \
        }

        if (powok) {
            SCAN_BODY({
                float p = exp2f(-delta * L2E);
                e[0] = p;
                _Pragma("unroll")
                for (int n = 1; n < 16; n++) e[n] = e[n-1] * p;
            })
        } else {
            SCAN_BODY({
                _Pragma("unroll")
                for (int n = 0; n < 16; n++) e[n] = exp2f(delta * A2[n]);
            })
        }
#undef SCAN_BODY
    }
    // no barrier: phase 6 touches only this thread's own u_s column + stable xs_s

    // ---- Phase 6: res half of in_proj + gating z = y * silu(res) (thread=d) ----
    {
        const int d = tid;
        float wr[64];
        const float4* wrow = (const float4*)(ip + (128 + d) * 64);
#pragma unroll
        for (int q = 0; q < 16; q++) {
            float4 v = wrow[q];
            wr[4*q+0] = v.x; wr[4*q+1] = v.y; wr[4*q+2] = v.z; wr[4*q+3] = v.w;
        }
        for (int tt = 0; tt < 48; tt++) {
            const float4* xrow = (const float4*)&xs_s[tt * 68];  // broadcast
            float acc = 0.f;
#pragma unroll
            for (int q = 0; q < 16; q++) {
                float4 v = xrow[q];
                acc += v.x * wr[4*q+0] + v.y * wr[4*q+1]
                     + v.z * wr[4*q+2] + v.w * wr[4*q+3];
            }
            int col = tt * 128 + ((((d >> 2) ^ (tt & 7)) << 2) | (d & 3));
            u_s[col] = u_s[col] * fast_silu(acc);
        }
    }
    __syncthreads();

    // ---- Phase 7: out_proj z(128) -> out(64), weighted accumulate (lane=t) ----
    if (t < 48) {
        float zr[128];
        const float4* zrow = (const float4*)&u_s[t * 128];
#pragma unroll
        for (int g = 0; g < 32; g++) {
            float4 v = zrow[g ^ (t & 7)];
            zr[4*g+0] = v.x; zr[4*g+1] = v.y; zr[4*g+2] = v.z; zr[4*g+3] = v.w;
        }
        for (int cc = 0; cc < 32; cc++) {
            int c = wv * 32 + cc;
            const float4* wrow = (const float4*)(op + c * 128);
            float acc = 0.f;
#pragma unroll
            for (int q = 0; q < 32; q++) {
                float4 w4 = wrow[q];
                acc += zr[4*q+0] * w4.x + zr[4*q+1] * w4.y
                     + zr[4*q+2] * w4.z + zr[4*q+3] * w4.w;
            }
            int oaddr = c * CS + base + t * TS;
            float vout = wdir * acc;
            if (!FIRST) vout += out[oaddr];
            out[oaddr] = vout;
        }
    }
}

extern "C" void kernel_launch(void* const* d_in, const int* in_sizes, int n_in,
                              void* d_out, int out_size, void* d_ws, size_t ws_size,
                              hipStream_t stream) {
    const float* x        = (const float*)d_in[0];
    const float* in_proj  = (const float*)d_in[1];
    const float* conv_w   = (const float*)d_in[2];
    const float* conv_b   = (const float*)d_in[3];
    const float* x_proj   = (const float*)d_in[4];
    const float* dt_w     = (const float*)d_in[5];
    const float* dt_b     = (const float*)d_in[6];
    const float* A_log    = (const float*)d_in[7];
    const float* D_ssm    = (const float*)d_in[8];
    const float* out_proj = (const float*)d_in[9];
    const float* ln_g     = (const float*)d_in[10];
    const float* ln_b     = (const float*)d_in[11];
    const float* alpha    = (const float*)d_in[12];
    float* out = (float*)d_out;

    dim3 grid(2304), block(128);
    mamba_dir<0, true ><<<grid, block, 0, stream>>>(x, in_proj, conv_w, conv_b, x_proj,
        dt_w, dt_b, A_log, D_ssm, out_proj, ln_g, ln_b, alpha, out);
    mamba_dir<1, false><<<grid, block, 0, stream>>>(x, in_proj, conv_w, conv_b, x_proj,
        dt_w, dt_b, A_log, D_ssm, out_proj, ln_g, ln_b, alpha, out);
    mamba_dir<2, false><<<grid, block, 0, stream>>>(x, in_proj, conv_w, conv_b, x_proj,
        dt_w, dt_b, A_log, D_ssm, out_proj, ln_g, ln_b, alpha, out);
}